// Round 6
// baseline (368.643 us; speedup 1.0000x reference)
//
#include <hip/hip_runtime.h>

// Binarized depthwise 3x3 conv, stride 1, SAME, NHWC, sign(0)=+1.
// x: (16,112,112,256) f32, kernel: (3,3,256,1) f32, out: (16,112,112,256) f32.
//
// Round 9: SINGLE-VARIABLE TEST -- identical to round 8 except the stores
// are regular (temporal) instead of __builtin_nontemporal_store. NT stores
// were present in EVERY prior variant (inherited from the earlier session);
// if the NT write path drains at ~1.7 TB/s, the 205 MB write stream alone
// is ~120 us -- exactly the floor that no read-side change (volume, MLP,
// occupancy, order) could break. Fill (6.5 TB/s) and float4 copy (6.29)
// both use regular stores.
//
// Structure (unchanged from round 8): block = 4 waves stages the sign bits
// of an 18-row x 16-col x 256-ch input tile into LDS (row-major issue
// order), then popc-computes 16 output rows x 14 cols with row-major
// linear store runs. sig[ci*C+ch] bit p = signbit x[n, h0-1+p, w0-1+ci, ch].
// Border rows masked by the per-row 3-bit window mask; border columns drop
// the whole kernel-column term at the slide edges.

constexpr int N = 16, H = 112, W = 112, C = 256;
constexpr int TW = 14;          // output cols per block; W/TW = 8
constexpr int COLS = TW + 2;    // staged sig columns
constexpr int RW = 4;           // output rows per wave; 4 waves -> 16 rows/block

typedef float f32x4 __attribute__((ext_vector_type(4)));

__global__ __launch_bounds__(256, 4) void bsign_dw3x3_tstore(
        const float* __restrict__ x, const float* __restrict__ k,
        float* __restrict__ out) {
    __shared__ unsigned sig[COLS * C];   // 16 KB

    const int lane = threadIdx.x & 63;
    const int wq   = threadIdx.x >> 6;
    const int c0   = lane << 2;          // 4 channels/lane, full C per wave
    const int h0   = blockIdx.y * 16;
    const int w0   = blockIdx.x * TW;
    const int n    = blockIdx.z;

    const size_t rowstride = (size_t)W * C;
    const bool ptop = (h0 > 0);          // row h0-1  exists (p=0)
    const bool pbot = (h0 + 16 < H);     // row h0+16 exists (p=17)

    // ---- Phase 1: stage sig columns, ROW-MAJOR issue order. ----
    // Wave wq owns sig columns ci = 4wq..4wq+3 (4 KB contiguous per row).
    const int ciB = wq << 2;
    const float* xbase = x + (size_t)(n * H + h0 - 1) * rowstride + c0;
    bool cv[4];
    const float* cp[4];
#pragma unroll
    for (int q = 0; q < 4; ++q) {
        const int xc = w0 - 1 + ciB + q;
        cv[q] = (xc >= 0 && xc < W);     // wave-uniform
        cp[q] = xbase + (ptrdiff_t)xc * (ptrdiff_t)C;
    }
    unsigned sq[4][4] = {{0,0,0,0},{0,0,0,0},{0,0,0,0},{0,0,0,0}};
#pragma unroll
    for (int p = 0; p < 18; ++p) {
        if (p == 0  && !ptop) continue;
        if (p == 17 && !pbot) continue;
        const size_t ro = (size_t)p * rowstride;
#pragma unroll
        for (int q = 0; q < 4; ++q) {
            if (cv[q]) {
                const uint4 v = *reinterpret_cast<const uint4*>(cp[q] + ro);
                sq[q][0] |= (v.x >> 31) << p;
                sq[q][1] |= (v.y >> 31) << p;
                sq[q][2] |= (v.z >> 31) << p;
                sq[q][3] |= (v.w >> 31) << p;
            }
        }
    }
#pragma unroll
    for (int q = 0; q < 4; ++q) {
        uint4 sv; sv.x = sq[q][0]; sv.y = sq[q][1]; sv.z = sq[q][2]; sv.w = sq[q][3];
        *reinterpret_cast<uint4*>(&sig[(ciB + q) * C + c0]) = sv;
    }

    // Kernel sign codes k3[j][ch]: bit i = signbit k[i][j].
    unsigned k3[3][4] = {{0,0,0,0},{0,0,0,0},{0,0,0,0}};
#pragma unroll
    for (int t = 0; t < 9; ++t) {
        const uint4 kv = *reinterpret_cast<const uint4*>(k + t * C + c0);
        const int kr = t / 3, kj = t % 3;
        k3[kj][0] |= (kv.x >> 31) << kr;
        k3[kj][1] |= (kv.y >> 31) << kr;
        k3[kj][2] |= (kv.z >> 31) << kr;
        k3[kj][3] |= (kv.w >> 31) << kr;
    }
    __syncthreads();

    // ---- Phase 2: popc compute, ROW-MAJOR store order, REGULAR stores. ----
    const int hbase = h0 + (wq << 2);
    float* obase = out + (size_t)(n * H + hbase) * rowstride
                       + (size_t)w0 * C + c0;
    const bool ledge = (w0 == 0), redge = (w0 + TW == W);

#pragma unroll
    for (int r = 0; r < RW; ++r) {
        const int h  = hbase + r;
        const unsigned b = (h == 0) ? 6u : (h == H - 1) ? 3u : 7u;
        const int nr = (h == 0 || h == H - 1) ? 2 : 3;
        const int sh = (wq << 2) + r;
        float* orow = obase + (size_t)r * rowstride;

        // Sliding per-term values: t_j(ci) = contribution of sig col ci as
        // kernel col j. out(wo) = t0(wo) + t1(wo+1) + t2(wo+2)  [ci-indexed].
        int t0m2[4], t0m1[4], t1m1[4], tj0[4], tj1[4], tj2[4];

        auto tcol = [&](int ci) {
            const uint4 v = *reinterpret_cast<const uint4*>(&sig[ci * C + c0]);
            const unsigned d[4] = {v.x >> sh, v.y >> sh, v.z >> sh, v.w >> sh};
#pragma unroll
            for (int ch = 0; ch < 4; ++ch) {
                tj0[ch] = nr - 2 * __popc((d[ch] ^ k3[0][ch]) & b);
                tj1[ch] = nr - 2 * __popc((d[ch] ^ k3[1][ch]) & b);
                tj2[ch] = nr - 2 * __popc((d[ch] ^ k3[2][ch]) & b);
            }
        };

        if (ledge) {
#pragma unroll
            for (int ch = 0; ch < 4; ++ch) t0m2[ch] = 0;
        } else {
            tcol(0);
#pragma unroll
            for (int ch = 0; ch < 4; ++ch) t0m2[ch] = tj0[ch];
        }
        tcol(1);
#pragma unroll
        for (int ch = 0; ch < 4; ++ch) { t0m1[ch] = tj0[ch]; t1m1[ch] = tj1[ch]; }

#pragma unroll
        for (int ci = 2; ci < COLS; ++ci) {
            if (ci == COLS - 1 && redge) {
#pragma unroll
                for (int ch = 0; ch < 4; ++ch) tj2[ch] = 0;
            } else {
                tcol(ci);
            }
            f32x4 ov;
#pragma unroll
            for (int ch = 0; ch < 4; ++ch)
                ov[ch] = (float)(t0m2[ch] + t1m1[ch] + tj2[ch]);
            *reinterpret_cast<f32x4*>(orow + (size_t)(ci - 2) * C) = ov;
#pragma unroll
            for (int ch = 0; ch < 4; ++ch) {
                t0m2[ch] = t0m1[ch]; t0m1[ch] = tj0[ch]; t1m1[ch] = tj1[ch];
            }
        }
    }
}

extern "C" void kernel_launch(void* const* d_in, const int* in_sizes, int n_in,
                              void* d_out, int out_size, void* d_ws, size_t ws_size,
                              hipStream_t stream) {
    const float* x = (const float*)d_in[0];   // (16,112,112,256) f32
    const float* k = (const float*)d_in[1];   // (3,3,256,1) f32
    float* out = (float*)d_out;               // (16,112,112,256) f32

    dim3 grid(W / TW, H / 16, N);             // (8, 7, 16) = 896 blocks
    bsign_dw3x3_tstore<<<grid, 256, 0, stream>>>(x, k, out);
}

// Round 7
// 364.154 us; speedup vs baseline: 1.0123x; 1.0123x over previous
//
#include <hip/hip_runtime.h>

// Binarized depthwise 3x3 conv, stride 1, SAME, NHWC, sign(0)=+1.
// x: (16,112,112,256) f32, kernel: (3,3,256,1) f32, out: (16,112,112,256) f32.
//
// Round 10: TWO PURE STREAMS via sign-bit workspace. Rounds 0-9 falsified
// volume/occupancy/MLP/order/NT-store theories one by one; the mixed
// read+compute+write kernel is pinned at ~2.5-3 TB/s HBM service while
// pure-write (fill, 6.5 TB/s) and lockstep copy (6.29 TB/s) hit ceiling.
// So: eliminate the mix. Kernel 1 is a pure linear READ stream (205 MB in,
// 6.4 MB bit-packed signs out to workspace). Kernel 2 is a pure linear
// WRITE stream (reads the 6.4 MB bitmap -- L2/L3-resident -- computes the
// popc window sums, writes 205 MB out).
//
// Bitmap layout: word[t] bit b = signbit(x[32t + b]), i.e.
// word[(n*H+h)*W*8 + w*8 + k] bit b = sign of channel 32k+b at (n,h,w).

constexpr int N = 16, H = 112, W = 112, C = 256;
constexpr int NWORDS = N * H * W * (C / 32);     // 1,605,632 u32 = 6.42 MB

typedef float f32x4 __attribute__((ext_vector_type(4)));

// ---------- Kernel 1: pure read stream -- pack sign bits ----------
// Thread t: reads x[32t .. 32t+31] (128 B contiguous), stores word[t].
__global__ __launch_bounds__(256, 4) void pack_signs(
        const float* __restrict__ x, unsigned* __restrict__ sw) {
    const int t = blockIdx.x * 256 + threadIdx.x;
    const float* p = x + (size_t)t * 32;
    unsigned wv = 0;
#pragma unroll
    for (int i = 0; i < 8; ++i) {
        const uint4 v = *reinterpret_cast<const uint4*>(p + i * 4);
        wv |= ((v.x >> 31) << (4 * i))     | ((v.y >> 31) << (4 * i + 1))
            | ((v.z >> 31) << (4 * i + 2)) | ((v.w >> 31) << (4 * i + 3));
    }
    sw[t] = wv;
}

// ---------- Kernel 2: pure write stream -- conv from bitmap ----------
// Block = one (n,h) row. Wave q owns w in [28q, 28q+28), lane owns 4
// channels c0=4*lane: bitmap word index wk=lane>>3, nibble shift
// nsh=4*(lane&7). Per column: 3 u32 loads (rows h-1,h,h+1, 32 B/wave,
// all cache-hits); per-channel 3-bit column signature vs 3-bit kernel
// column code; tap sum = nr - 2*popc(xor & rowmask). Sliding window
// over w; stores are 1 KB/wave contiguous, 28 KB linear per wave.
__global__ __launch_bounds__(256, 4) void conv_from_bits(
        const unsigned* __restrict__ sw, const float* __restrict__ k,
        float* __restrict__ out) {
    const int h    = blockIdx.x;
    const int n    = blockIdx.y;
    const int lane = threadIdx.x & 63;
    const int wq   = threadIdx.x >> 6;
    const int w0   = wq * 28;
    const int c0   = lane << 2;
    const int wk   = lane >> 3;
    const int nsh  = (lane & 7) << 2;

    // Kernel sign codes k3[j][ch]: bit i = signbit k[i][j].
    unsigned k3[3][4] = {{0,0,0,0},{0,0,0,0},{0,0,0,0}};
#pragma unroll
    for (int t = 0; t < 9; ++t) {
        const uint4 kv = *reinterpret_cast<const uint4*>(k + t * C + c0);
        const int kr = t / 3, kj = t % 3;
        k3[kj][0] |= (kv.x >> 31) << kr;
        k3[kj][1] |= (kv.y >> 31) << kr;
        k3[kj][2] |= (kv.z >> 31) << kr;
        k3[kj][3] |= (kv.w >> 31) << kr;
    }

    const bool htop = (h > 0), hbot = (h < H - 1);
    const unsigned bm = !htop ? 6u : !hbot ? 3u : 7u;   // valid-row mask
    const int nr = (htop && hbot) ? 3 : 2;

    const unsigned* wrow = sw + ((size_t)(n * H + h) * W) * 8 + wk;
    constexpr ptrdiff_t RS = (ptrdiff_t)W * 8;          // bitmap row stride
    float* obase = out + (((size_t)(n * H + h) * W) + w0) * C + c0;

    // Per-column term values tj0/tj1/tj2 = contribution of this column as
    // kernel column 0/1/2, per channel.
    int t0m2[4], t0m1[4], t1m1[4], a0[4], a1[4], a2[4];

    auto tcol = [&](int cc) {
        const unsigned wc = wrow[(ptrdiff_t)cc * 8];
        unsigned wm = 0, wp = 0;
        if (htop) wm = wrow[(ptrdiff_t)cc * 8 - RS];
        if (hbot) wp = wrow[(ptrdiff_t)cc * 8 + RS];
#pragma unroll
        for (int ch = 0; ch < 4; ++ch) {
            const unsigned cs = ((wm >> (nsh + ch)) & 1u)
                              | (((wc >> (nsh + ch)) & 1u) << 1)
                              | (((wp >> (nsh + ch)) & 1u) << 2);
            a0[ch] = nr - 2 * __popc((cs ^ k3[0][ch]) & bm);
            a1[ch] = nr - 2 * __popc((cs ^ k3[1][ch]) & bm);
            a2[ch] = nr - 2 * __popc((cs ^ k3[2][ch]) & bm);
        }
    };

    const bool ledge = (w0 == 0), redge = (w0 + 28 == W);

    if (ledge) {
#pragma unroll
        for (int ch = 0; ch < 4; ++ch) t0m2[ch] = 0;
    } else {
        tcol(w0 - 1);
#pragma unroll
        for (int ch = 0; ch < 4; ++ch) t0m2[ch] = a0[ch];
    }
    tcol(w0);
#pragma unroll
    for (int ch = 0; ch < 4; ++ch) { t0m1[ch] = a0[ch]; t1m1[ch] = a1[ch]; }

#pragma unroll 4
    for (int cc = w0 + 1; cc <= w0 + 28; ++cc) {
        if (redge && cc == W) {
#pragma unroll
            for (int ch = 0; ch < 4; ++ch) a2[ch] = 0;
        } else {
            tcol(cc);
        }
        f32x4 ov;
#pragma unroll
        for (int ch = 0; ch < 4; ++ch)
            ov[ch] = (float)(t0m2[ch] + t1m1[ch] + a2[ch]);
        *reinterpret_cast<f32x4*>(obase + (size_t)(cc - 1 - w0) * C) = ov;
#pragma unroll
        for (int ch = 0; ch < 4; ++ch) {
            t0m2[ch] = t0m1[ch]; t0m1[ch] = a0[ch]; t1m1[ch] = a1[ch];
        }
    }
}

// ---------- Fallback (only if workspace is too small): direct compute ----------
__global__ __launch_bounds__(256) void bsign_direct(
        const float* __restrict__ x, const float* __restrict__ k,
        float* __restrict__ out) {
    const int idx = blockIdx.x * 256 + threadIdx.x;   // one f32x4 per thread
    const int c0  = (idx & 63) << 2;
    const int pos = idx >> 6;
    const int w   = pos % W;
    const int h   = (pos / W) % H;
    const int n   = pos / (W * H);

    int acc[4] = {0, 0, 0, 0};
#pragma unroll
    for (int dr = -1; dr <= 1; ++dr) {
#pragma unroll
        for (int dc = -1; dc <= 1; ++dc) {
            const int hh = h + dr, ww = w + dc;
            if (hh < 0 || hh >= H || ww < 0 || ww >= W) continue;
            const uint4 xv = *reinterpret_cast<const uint4*>(
                x + (((size_t)(n * H + hh) * W) + ww) * C + c0);
            const uint4 kv = *reinterpret_cast<const uint4*>(
                k + ((dr + 1) * 3 + (dc + 1)) * C + c0);
            acc[0] += 1 - 2 * (int)((xv.x ^ kv.x) >> 31);
            acc[1] += 1 - 2 * (int)((xv.y ^ kv.y) >> 31);
            acc[2] += 1 - 2 * (int)((xv.z ^ kv.z) >> 31);
            acc[3] += 1 - 2 * (int)((xv.w ^ kv.w) >> 31);
        }
    }
    f32x4 ov;
#pragma unroll
    for (int ch = 0; ch < 4; ++ch) ov[ch] = (float)acc[ch];
    *reinterpret_cast<f32x4*>(
        out + (((size_t)(n * H + h) * W) + w) * C + c0) = ov;
}

extern "C" void kernel_launch(void* const* d_in, const int* in_sizes, int n_in,
                              void* d_out, int out_size, void* d_ws, size_t ws_size,
                              hipStream_t stream) {
    const float* x = (const float*)d_in[0];   // (16,112,112,256) f32
    const float* k = (const float*)d_in[1];   // (3,3,256,1) f32
    float* out = (float*)d_out;               // (16,112,112,256) f32

    if (ws_size >= (size_t)NWORDS * 4 && d_ws != nullptr) {
        unsigned* sw = (unsigned*)d_ws;
        pack_signs<<<dim3(NWORDS / 256), 256, 0, stream>>>(x, sw);
        conv_from_bits<<<dim3(H, N), 256, 0, stream>>>(sw, k, out);
    } else {
        // Workspace too small: slow but correct direct path.
        bsign_direct<<<dim3(N * H * W * 64 / 256), 256, 0, stream>>>(x, k, out);
    }
}